// Round 1
// baseline (968.440 us; speedup 1.0000x reference)
//
#include <hip/hip_runtime.h>
#include <cstdint>
#include <cstddef>

// MultiHeadSelfAttention: B=4 H=16 S=2048 D=1024 d=64
// d_out = [output fp32 (4,2048,1024)] ++ [attn_weights fp32 (4,16,2048,2048)]
//
// Pipeline (all bf16 MFMA, fp32 accum/softmax):
//   cvt x,w* -> bf16 | GEMM Q,K (bf16) | GEMM V -> V^T per head (bf16)
//   attn: 2-pass softmax (online max/sum, then recompute+write weights+PV)
//   GEMM out-proj -> d_out fp32

#define D_MODEL 1024
#define NHEADS  16
#define HDIM    64
#define BATCH   4
#define SEQ     2048
#define NTOK    (BATCH*SEQ)   // 8192

typedef __bf16 bf16x8 __attribute__((ext_vector_type(8)));
typedef float  f32x4  __attribute__((ext_vector_type(4)));
typedef unsigned short u16x8 __attribute__((ext_vector_type(8)));

__device__ __forceinline__ uint16_t f2bf(float f) {
  union { float f; uint32_t u; } v; v.f = f;
  return (uint16_t)((v.u + 0x7FFFu + ((v.u >> 16) & 1u)) >> 16);
}
__device__ __forceinline__ bf16x8 ldbf8(const uint16_t* p) {
  return __builtin_bit_cast(bf16x8, *(const u16x8*)p);
}

// ---------------- fp32 -> bf16 convert ----------------
__global__ __launch_bounds__(256) void cvt_kernel(const float* __restrict__ src,
                                                  uint16_t* __restrict__ dst, int n4) {
  int i = blockIdx.x * blockDim.x + threadIdx.x;
  if (i < n4) {
    float4 f = ((const float4*)src)[i];
    ushort4 o;
    o.x = f2bf(f.x); o.y = f2bf(f.y); o.z = f2bf(f.z); o.w = f2bf(f.w);
    ((ushort4*)dst)[i] = o;
  }
}

// ---------------- GEMM: out[m,n] = sum_k A[m,k]*Bt[n,k] + bias[n] ----------------
// A: [M,K] bf16 row-major; Bt: [N,K] bf16 row-major (i.e. W, used as x@W^T).
// MODE 0: out bf16 [M,N]. MODE 1: out bf16 V^T per head: [(b,h,d),s].
// MODE 2: out fp32 [M,N].
// 128x128 tile, BK=64, 256 thr (4 waves 2x2, each 64x64 = 4x4 MFMA tiles).
template <int MODE>
__global__ __launch_bounds__(256)
void gemm_bt(const uint16_t* __restrict__ A, const uint16_t* __restrict__ Bt,
             const float* __restrict__ bias, void* __restrict__ out,
             int M, int N, int K) {
  __shared__ uint16_t As[128 * 72];  // +8 bf16 pad: row stride 144B -> 2-way max
  __shared__ uint16_t Bs[128 * 72];
  const int tid  = threadIdx.x;
  const int lane = tid & 63;
  const int wave = tid >> 6;
  const int wr = wave >> 1, wc = wave & 1;
  const int m0 = blockIdx.y * 128, n0 = blockIdx.x * 128;
  const int lrow = lane & 15;
  const int lk8  = (lane >> 4) * 8;

  f32x4 acc[4][4] = {};

  for (int k0 = 0; k0 < K; k0 += 64) {
#pragma unroll
    for (int it = 0; it < 4; ++it) {
      int c = tid + it * 256;          // 0..1023
      int row = c >> 3, kc = (c & 7) * 8;
      *(u16x8*)&As[row * 72 + kc] = *(const u16x8*)&A [(size_t)(m0 + row) * K + k0 + kc];
      *(u16x8*)&Bs[row * 72 + kc] = *(const u16x8*)&Bt[(size_t)(n0 + row) * K + k0 + kc];
    }
    __syncthreads();
#pragma unroll
    for (int ks = 0; ks < 2; ++ks) {
      bf16x8 af[4], bfr[4];
#pragma unroll
      for (int i = 0; i < 4; ++i) {
        af [i] = ldbf8(&As[(wr * 64 + i * 16 + lrow) * 72 + ks * 32 + lk8]);
        bfr[i] = ldbf8(&Bs[(wc * 64 + i * 16 + lrow) * 72 + ks * 32 + lk8]);
      }
#pragma unroll
      for (int i = 0; i < 4; ++i)
#pragma unroll
        for (int j = 0; j < 4; ++j)
          acc[i][j] = __builtin_amdgcn_mfma_f32_16x16x32_bf16(af[i], bfr[j], acc[i][j], 0, 0, 0);
    }
    __syncthreads();
  }

  const int r0 = (lane >> 4) * 4;
#pragma unroll
  for (int i = 0; i < 4; ++i) {
#pragma unroll
    for (int j = 0; j < 4; ++j) {
      int gmb = m0 + wr * 64 + i * 16 + r0;
      int gn  = n0 + wc * 64 + j * 16 + lrow;
      float bv = bias[gn];
#pragma unroll
      for (int r = 0; r < 4; ++r) {
        float v = acc[i][j][r] + bv;
        int gm = gmb + r;
        if (MODE == 0) {
          ((uint16_t*)out)[(size_t)gm * N + gn] = f2bf(v);
        } else if (MODE == 1) {
          int b = gm >> 11, s = gm & (SEQ - 1);
          int h = gn >> 6,  d = gn & (HDIM - 1);
          ((uint16_t*)out)[(((size_t)(b * NHEADS + h) * HDIM + d) << 11) + s] = f2bf(v);
        } else {
          ((float*)out)[(size_t)gm * N + gn] = v;
        }
      }
    }
  }
}

// ---------------- Attention ----------------
// grid (S/64, H, B), 256 thr = 4 waves; wave handles 16 q rows.
// Pass A: online row max m and sum l over all 2048 keys.
// Pass B: recompute scores, write normalized weights (fp32), PV via MFMA with V^T.
__global__ __launch_bounds__(256)
void attn_kernel(const uint16_t* __restrict__ Q, const uint16_t* __restrict__ Kb,
                 const uint16_t* __restrict__ Vt, float* __restrict__ attnw,
                 uint16_t* __restrict__ ctx) {
  __shared__ uint16_t plds[4][16][40];  // per-wave P staging, stride 80B (bank-spread)
  const int tid  = threadIdx.x;
  const int lane = tid & 63;
  const int wave = tid >> 6;
  const int qt = blockIdx.x, h = blockIdx.y, b = blockIdx.z;
  const int q0 = qt * 64 + wave * 16;
  const int lrow = lane & 15;
  const int lk8  = (lane >> 4) * 8;
  const int r0   = (lane >> 4) * 4;
  const float scale = 0.125f;  // 1/sqrt(64)

  const size_t qbase = ((size_t)(b * SEQ) + q0 + lrow) * D_MODEL + h * HDIM;
  bf16x8 qf[2];
  qf[0] = ldbf8(&Q[qbase + lk8]);
  qf[1] = ldbf8(&Q[qbase + 32 + lk8]);

  const uint16_t* Kh = Kb + (size_t)(b * SEQ) * D_MODEL + h * HDIM;       // K[s*1024 + d]
  const uint16_t* Vh = Vt + ((size_t)(b * NHEADS + h) * HDIM) * SEQ;      // V^T[d*2048 + s]

  float mrow[4] = {-INFINITY, -INFINITY, -INFINITY, -INFINITY};
  float lsum[4] = {0.f, 0.f, 0.f, 0.f};

  // ---- pass A: max + sum ----
  for (int kt = 0; kt < SEQ / 16; ++kt) {
    const size_t kb = (size_t)(kt * 16 + lrow) * D_MODEL + lk8;
    f32x4 s = {};
    s = __builtin_amdgcn_mfma_f32_16x16x32_bf16(qf[0], ldbf8(&Kh[kb]),      s, 0, 0, 0);
    s = __builtin_amdgcn_mfma_f32_16x16x32_bf16(qf[1], ldbf8(&Kh[kb + 32]), s, 0, 0, 0);
#pragma unroll
    for (int r = 0; r < 4; ++r) {
      float v = s[r] * scale;
      float t = v;
      t = fmaxf(t, __shfl_xor(t, 1)); t = fmaxf(t, __shfl_xor(t, 2));
      t = fmaxf(t, __shfl_xor(t, 4)); t = fmaxf(t, __shfl_xor(t, 8));
      float mn = fmaxf(mrow[r], t);
      float p = __expf(v - mn);
      p += __shfl_xor(p, 1); p += __shfl_xor(p, 2);
      p += __shfl_xor(p, 4); p += __shfl_xor(p, 8);
      lsum[r] = lsum[r] * __expf(mrow[r] - mn) + p;
      mrow[r] = mn;
    }
  }
  float rinv[4];
#pragma unroll
  for (int r = 0; r < 4; ++r) rinv[r] = 1.0f / lsum[r];

  // ---- pass B: weights + PV ----
  f32x4 cacc[4] = {};
  float* aw = attnw + (((size_t)(b * NHEADS + h)) * SEQ + q0) * SEQ;
  for (int kc = 0; kc < SEQ / 32; ++kc) {
    const int kbase = kc * 32;
    const size_t kb0 = (size_t)(kbase + lrow) * D_MODEL + lk8;
    const size_t kb1 = (size_t)(kbase + 16 + lrow) * D_MODEL + lk8;
    f32x4 s0 = {}, s1 = {};
    s0 = __builtin_amdgcn_mfma_f32_16x16x32_bf16(qf[0], ldbf8(&Kh[kb0]),      s0, 0, 0, 0);
    s0 = __builtin_amdgcn_mfma_f32_16x16x32_bf16(qf[1], ldbf8(&Kh[kb0 + 32]), s0, 0, 0, 0);
    s1 = __builtin_amdgcn_mfma_f32_16x16x32_bf16(qf[0], ldbf8(&Kh[kb1]),      s1, 0, 0, 0);
    s1 = __builtin_amdgcn_mfma_f32_16x16x32_bf16(qf[1], ldbf8(&Kh[kb1 + 32]), s1, 0, 0, 0);
#pragma unroll
    for (int r = 0; r < 4; ++r) {
      float p0 = __expf(s0[r] * scale - mrow[r]) * rinv[r];
      float p1 = __expf(s1[r] * scale - mrow[r]) * rinv[r];
      aw[(size_t)(r0 + r) * SEQ + kbase + lrow]      = p0;
      aw[(size_t)(r0 + r) * SEQ + kbase + 16 + lrow] = p1;
      plds[wave][r0 + r][lrow]      = f2bf(p0);
      plds[wave][r0 + r][16 + lrow] = f2bf(p1);
    }
    // wave-local LDS cross-lane: drain DS writes before the fragment read
    asm volatile("s_waitcnt lgkmcnt(0)" ::: "memory");
    bf16x8 pf = ldbf8(&plds[wave][lrow][lk8]);
#pragma unroll
    for (int n = 0; n < 4; ++n) {
      bf16x8 vf = ldbf8(&Vh[(size_t)(n * 16 + lrow) * SEQ + kbase + lk8]);
      cacc[n] = __builtin_amdgcn_mfma_f32_16x16x32_bf16(pf, vf, cacc[n], 0, 0, 0);
    }
  }
  // ctx: rebuild [tok, 1024] bf16
#pragma unroll
  for (int n = 0; n < 4; ++n)
#pragma unroll
    for (int r = 0; r < 4; ++r) {
      int gq = q0 + r0 + r;
      ctx[((size_t)(b * SEQ) + gq) * D_MODEL + h * HDIM + n * 16 + lrow] = f2bf(cacc[n][r]);
    }
}

// ---------------- launch ----------------
extern "C" void kernel_launch(void* const* d_in, const int* in_sizes, int n_in,
                              void* d_out, int out_size, void* d_ws, size_t ws_size,
                              hipStream_t stream) {
  const float* x  = (const float*)d_in[0];
  const float* wq = (const float*)d_in[1];
  const float* bq = (const float*)d_in[2];
  const float* wk = (const float*)d_in[3];
  const float* bk = (const float*)d_in[4];
  const float* wv = (const float*)d_in[5];
  const float* bv = (const float*)d_in[6];
  const float* wo = (const float*)d_in[7];
  const float* bo = (const float*)d_in[8];

  char* ws = (char*)d_ws;
  uint16_t* xb  = (uint16_t*)ws;                      // 16 MB (reused as ctx after QKV GEMMs)
  uint16_t* wqb = (uint16_t*)(ws + (16u << 20));
  uint16_t* wkb = (uint16_t*)(ws + (18u << 20));
  uint16_t* wvb = (uint16_t*)(ws + (20u << 20));
  uint16_t* wob = (uint16_t*)(ws + (22u << 20));
  uint16_t* Qb  = (uint16_t*)(ws + (24u << 20));      // 16 MB
  uint16_t* Kc  = (uint16_t*)(ws + (40u << 20));      // 16 MB
  uint16_t* Vtb = (uint16_t*)(ws + (56u << 20));      // 16 MB -> total 72 MB
  uint16_t* ctx = xb;  // x dead after QKV GEMMs; stream order serializes

  float* outp  = (float*)d_out;
  float* attnw = outp + (size_t)NTOK * D_MODEL;

  // converts
  {
    int n4 = (NTOK * D_MODEL) / 4;
    cvt_kernel<<<(n4 + 255) / 256, 256, 0, stream>>>(x, xb, n4);
    int w4 = (D_MODEL * D_MODEL) / 4;
    cvt_kernel<<<(w4 + 255) / 256, 256, 0, stream>>>(wq, wqb, w4);
    cvt_kernel<<<(w4 + 255) / 256, 256, 0, stream>>>(wk, wkb, w4);
    cvt_kernel<<<(w4 + 255) / 256, 256, 0, stream>>>(wv, wvb, w4);
    cvt_kernel<<<(w4 + 255) / 256, 256, 0, stream>>>(wo, wob, w4);
  }

  dim3 ggrid(D_MODEL / 128, NTOK / 128);  // (8, 64)
  gemm_bt<0><<<ggrid, 256, 0, stream>>>(xb, wqb, bq, (void*)Qb,  NTOK, D_MODEL, D_MODEL);
  gemm_bt<0><<<ggrid, 256, 0, stream>>>(xb, wkb, bk, (void*)Kc,  NTOK, D_MODEL, D_MODEL);
  gemm_bt<1><<<ggrid, 256, 0, stream>>>(xb, wvb, bv, (void*)Vtb, NTOK, D_MODEL, D_MODEL);

  dim3 agrid(SEQ / 64, NHEADS, BATCH);    // (32, 16, 4)
  attn_kernel<<<agrid, 256, 0, stream>>>(Qb, Kc, Vtb, attnw, ctx);

  gemm_bt<2><<<ggrid, 256, 0, stream>>>(ctx, wob, bo, (void*)outp, NTOK, D_MODEL, D_MODEL);
}